// Round 5
// baseline (487.320 us; speedup 1.0000x reference)
//
#include <hip/hip_runtime.h>
#include <hip/hip_bf16.h>
#include <stdint.h>

#define B_   16
#define LW_  512
#define LE_  128
#define L_   640
#define D_   1024
#define H_   16
#define DH_  64
#define M_   (B_*L_)     // 10240
#define N_   (7*D_)      // 7168
#define K_   D_          // 1024

typedef __attribute__((ext_vector_type(8))) short short8;
typedef __attribute__((ext_vector_type(4))) float float4v;

__device__ __forceinline__ unsigned short f2bf(float x){
    union { float f; uint32_t u; } v; v.f = x;
    uint32_t u = v.u;
    return (unsigned short)((u + 0x7FFFu + ((u >> 16) & 1u)) >> 16);
}

// ------- prep: concat + cast hidden states to bf16 (+ fused bias concat) ----
__global__ __launch_bounds__(256) void prep_h(const float* __restrict__ word,
                                              const float* __restrict__ ent,
                                              unsigned short* __restrict__ hb,
                                              const float* __restrict__ b0, const float* __restrict__ b1,
                                              const float* __restrict__ b2, const float* __restrict__ b3,
                                              const float* __restrict__ b4, const float* __restrict__ b5,
                                              const float* __restrict__ b6,
                                              float* __restrict__ biasAll){
    if (blockIdx.x >= 5120) {
        int n = (blockIdx.x - 5120)*256 + threadIdx.x;   // 0..7167
        int p = n >> 10, c = n & 1023;
        const float* bp = (p==0)?b0:(p==1)?b1:(p==2)?b2:(p==3)?b3:(p==4)?b4:(p==5)?b5:b6;
        biasAll[n] = bp[c];
        return;
    }
    int idx = blockIdx.x*256 + threadIdx.x;   // one 8-elem group
    int row = idx >> 7;                       // 128 groups per 1024-row
    int c   = (idx & 127) << 3;
    int b = row / L_, l = row - b*L_;
    const float* src = (l < LW_) ? (word + ((size_t)b*LW_ + l)*D_ + c)
                                 : (ent  + ((size_t)b*LE_ + (l-LW_))*D_ + c);
    float4 a0 = ((const float4*)src)[0];
    float4 a1 = ((const float4*)src)[1];
    uint4 o;
    o.x = f2bf(a0.x) | ((uint32_t)f2bf(a0.y)<<16);
    o.y = f2bf(a0.z) | ((uint32_t)f2bf(a0.w)<<16);
    o.z = f2bf(a1.x) | ((uint32_t)f2bf(a1.y)<<16);
    o.w = f2bf(a1.z) | ((uint32_t)f2bf(a1.w)<<16);
    *(uint4*)(hb + (size_t)row*D_ + c) = o;
}

// ---------------- prep: transpose + cast weights -> Bt[7168][1024] bf16 ----
__global__ __launch_bounds__(256) void prep_w(const float* __restrict__ w0, const float* __restrict__ w1,
                                              const float* __restrict__ w2, const float* __restrict__ w3,
                                              const float* __restrict__ w4, const float* __restrict__ w5,
                                              const float* __restrict__ w6,
                                              unsigned short* __restrict__ bt){
    __shared__ float t[64][65];
    int id = blockIdx.x;
    int kt = id & 15;           // 16 k-tiles of 64
    int ntile = id >> 4;        // 112 n-tiles of 64
    int p = ntile >> 4;         // projection index
    int nin = (ntile & 15) * 64;
    const float* wp = (p==0)?w0:(p==1)?w1:(p==2)?w2:(p==3)?w3:(p==4)?w4:(p==5)?w5:w6;
    int k0 = kt*64;
    int tr  = threadIdx.x >> 4;        // 0..15
    int tc4 = (threadIdx.x & 15) * 4;  // 0..60
    for (int pass = 0; pass < 4; ++pass){
        int kl = pass*16 + tr;
        const float4 v = *(const float4*)(wp + (size_t)(k0+kl)*D_ + nin + tc4);
        t[kl][tc4+0]=v.x; t[kl][tc4+1]=v.y; t[kl][tc4+2]=v.z; t[kl][tc4+3]=v.w;
    }
    __syncthreads();
    for (int pass = 0; pass < 4; ++pass){
        int nl = pass*16 + tr;
        uint2 pk;
        pk.x = f2bf(t[tc4+0][nl]) | ((uint32_t)f2bf(t[tc4+1][nl])<<16);
        pk.y = f2bf(t[tc4+2][nl]) | ((uint32_t)f2bf(t[tc4+3][nl])<<16);
        *(uint2*)(bt + (size_t)(ntile*64 + nl)*K_ + k0 + tc4) = pk;
    }
}

// ---------------- projection GEMM (packed tile list) ------------------------
// Skips gate-projection tiles on rows that are never read:
//   proj3 (w2e_q): word rows only; proj4 (w2e_k): entity only;
//   proj5 (e2w_q): entity only;   proj6 (e2w_k): word only.
// 1920 qkv tiles + 512 + 128 + 128 + 512 = 3200 blocks (was 4480).
__global__ __launch_bounds__(256, 4) void gemm_proj(const unsigned short* __restrict__ hb,
                                                    const unsigned short* __restrict__ bt,
                                                    const float* __restrict__ biasAll,
                                                    unsigned short* __restrict__ C,
                                                    unsigned short* __restrict__ Vt){
    __shared__ unsigned short sA[128*64];
    __shared__ unsigned short sB[128*64];
    int tid = threadIdx.x;
    int wave = tid >> 6, lane = tid & 63;
    int quad = lane >> 4, l16 = lane & 15;

    int bid = blockIdx.x;
    int m0, n0;
    if (bid < 1920) { int bm = bid % 80, bn = bid / 80; m0 = bm*128; n0 = bn*128; }
    else {
        int g = bid - 1920;
        if (g < 512)      { int mt = g & 63; m0 = (mt>>2)*640 + (mt&3)*128; n0 = 3072 + (g>>6)*128; }
        else if (g < 640) { int e = g-512;   m0 = (e&15)*640 + 512;         n0 = 4096 + (e>>4)*128; }
        else if (g < 768) { int e = g-640;   m0 = (e&15)*640 + 512;         n0 = 5120 + (e>>4)*128; }
        else              { int e = g-768; int mt = e & 63;
                            m0 = (mt>>2)*640 + (mt&3)*128;                  n0 = 6144 + (e>>6)*128; }
    }

    int wm = wave >> 1, wn = wave & 1;
    float4v acc[4][4] = {};

    for (int kk = 0; kk < K_; kk += 64) {
        #pragma unroll
        for (int i = 0; i < 4; ++i) {
            int idx = i*256 + tid;
            int row = idx >> 3;
            int c8  = (((idx & 7) ^ (row & 7)) << 3);   // swizzled global chunk
            const unsigned short* ga = hb + (size_t)(m0 + row)*K_ + kk + c8;
            __builtin_amdgcn_global_load_lds(
                (const __attribute__((address_space(1))) void*)ga,
                (__attribute__((address_space(3))) void*)(sA + ((i*256 + wave*64) << 3)), 16, 0, 0);
            const unsigned short* gb = bt + (size_t)(n0 + row)*K_ + kk + c8;
            __builtin_amdgcn_global_load_lds(
                (const __attribute__((address_space(1))) void*)gb,
                (__attribute__((address_space(3))) void*)(sB + ((i*256 + wave*64) << 3)), 16, 0, 0);
        }
        __syncthreads();
        #pragma unroll
        for (int s = 0; s < 2; ++s) {
            short8 af[4], bf[4];
            #pragma unroll
            for (int i=0;i<4;i++){
                int row = wm*64 + i*16 + l16;
                af[i] = *(const short8*)(sA + (row << 6) + (((s*4 + quad) ^ (row & 7)) << 3));
            }
            #pragma unroll
            for (int j=0;j<4;j++){
                int row = wn*64 + j*16 + l16;
                bf[j] = *(const short8*)(sB + (row << 6) + (((s*4 + quad) ^ (row & 7)) << 3));
            }
            #pragma unroll
            for (int i=0;i<4;i++)
                #pragma unroll
                for (int j=0;j<4;j++)
                    acc[i][j] = __builtin_amdgcn_mfma_f32_16x16x32_bf16(af[i], bf[j], acc[i][j], 0,0,0);
        }
        __syncthreads();
    }

    bool isV = (n0 >= 2*D_) && (n0 < 3*D_);   // V projection tile -> write transposed
    #pragma unroll
    for (int i=0;i<4;i++){
        int mrow = m0 + wm*64 + i*16 + quad*4;
        #pragma unroll
        for (int j=0;j<4;j++){
            int ncol = n0 + wn*64 + j*16 + l16;
            float bias = biasAll[ncol];
            if (!isV) {
                #pragma unroll
                for (int r=0;r<4;r++)
                    C[(size_t)(mrow + r)*N_ + ncol] = f2bf(acc[i][j][r] + bias);
            } else {
                int nv = ncol - 2*D_;
                int hh = nv >> 6, dd = nv & 63;
                int bb = mrow / L_, ll = mrow - bb*L_;   // 4 rows stay in one b (mrow%4==0)
                uint2 pk;
                pk.x = f2bf(acc[i][j][0]+bias) | ((uint32_t)f2bf(acc[i][j][1]+bias)<<16);
                pk.y = f2bf(acc[i][j][2]+bias) | ((uint32_t)f2bf(acc[i][j][3]+bias)<<16);
                *(uint2*)(Vt + ((size_t)(bb*H_ + hh)*DH_ + dd)*L_ + ll) = pk;
            }
        }
    }
}

// ---------------- fused gated flash attention (v5) -------------------------
// V fragments load directly from global (Vt is 21 MB, L2/L3-hot) -> no sV LDS.
// LDS 43.5 KB -> 3 blocks/CU. K/GK double-buffered global_load_lds prefetch,
// one barrier per step. No online max (logits bounded; m=0 fixed).

__device__ __forceinline__ void tile_ld(const unsigned short* __restrict__ g, size_t stride,
                                        unsigned short* lds, int wave, int lane){
    #pragma unroll
    for (int p = 0; p < 2; ++p){
        int c = p*256 + wave*64 + lane;
        int r = c >> 3, js = c & 7;
        const unsigned short* ga = g + (size_t)r*stride + ((js ^ (r & 7)) << 3);
        __builtin_amdgcn_global_load_lds(
            (const __attribute__((address_space(1))) void*)ga,
            (__attribute__((address_space(3))) void*)(lds + ((p*256 + wave*64) << 3)), 16, 0, 0);
    }
}

__device__ __forceinline__ short8 frag64(const unsigned short* lds, int row, int jj){
    return *(const short8*)(lds + (row << 6) + (((jj ^ (row & 7)) << 3)));
}

__global__ __launch_bounds__(256, 3) void attn(const unsigned short* __restrict__ C,
                                               const unsigned short* __restrict__ Vt,
                                               const float* __restrict__ mask,
                                               float* __restrict__ out){
    int id = blockIdx.x;
    int qt = id % 5; id /= 5;
    int h  = id % H_; int b = id / H_;
    bool isWord = (qt < 4);
    int tid = threadIdx.x, wave = tid>>6, lane = tid&63, quad = lane>>4, l16 = lane&15;

    __shared__ unsigned short sK0 [64*64];
    __shared__ unsigned short sK1 [64*64];
    __shared__ unsigned short sGK0[64*64];
    __shared__ unsigned short sGK1[64*64];
    __shared__ unsigned short sP  [64*64];     // reused across mi, wave-local
    __shared__ float sMask[L_];

    const unsigned short* Kg  = C  + (size_t)(b*L_)*N_ + D_ + h*DH_;
    const unsigned short* GKg = C  + (size_t)(b*L_)*N_ + (isWord?4:6)*D_ + h*DH_;
    const unsigned short* Vg  = Vt + ((size_t)(b*H_ + h)*DH_)*L_;

    // preload kt=0
    tile_ld(Kg, N_, sK0, wave, lane);
    if (!isWord) tile_ld(GKg, N_, sGK0, wave, lane);

    // stage mask row for this b
    for (int i = tid; i < L_; i += 256) sMask[i] = mask[b*L_ + i];

    // Q / gateQ A-fragments (persist across k-loop)
    int qrowbase = b*L_ + qt*128 + wave*32;
    short8 qf[2][2], gqf[2][2];
    #pragma unroll
    for (int mi=0; mi<2; ++mi){
        const unsigned short* qb_ = C + (size_t)(qrowbase + mi*16 + l16)*N_ + h*DH_;
        const unsigned short* gq_ = C + (size_t)(qrowbase + mi*16 + l16)*N_ + (isWord?3:5)*D_ + h*DH_;
        qf[mi][0]  = *(const short8*)(qb_ + quad*8);
        qf[mi][1]  = *(const short8*)(qb_ + 32 + quad*8);
        gqf[mi][0] = *(const short8*)(gq_ + quad*8);
        gqf[mi][1] = *(const short8*)(gq_ + 32 + quad*8);
    }

    float4v O[2][4] = {};
    float lrow[2][4] = {};

    __syncthreads();   // drains preload + mask staging

    auto step = [&](int kt,
                    unsigned short* sKc, unsigned short* sGKc,
                    unsigned short* sKn, unsigned short* sGKn){
        // prefetch kt+1 into the other (statically distinct) buffer set
        if (kt < 9) {
            tile_ld(Kg + (size_t)((kt+1)*64)*N_, N_, sKn, wave, lane);
            bool g1 = isWord ? (kt+1 >= 8) : (kt+1 < 8);
            if (g1) tile_ld(GKg + (size_t)((kt+1)*64)*N_, N_, sGKn, wave, lane);
        }
        bool gated = isWord ? (kt >= 8) : (kt < 8);

        // S = Q K^T  — K frags read once, used for both mi
        float4v S[2][4];
        #pragma unroll
        for (int nt=0; nt<4; ++nt){
            short8 k0 = frag64(sKc, nt*16 + l16, quad);
            short8 k1 = frag64(sKc, nt*16 + l16, 4 + quad);
            #pragma unroll
            for (int mi=0; mi<2; ++mi){
                float4v s = {};
                s = __builtin_amdgcn_mfma_f32_16x16x32_bf16(qf[mi][0], k0, s, 0,0,0);
                s = __builtin_amdgcn_mfma_f32_16x16x32_bf16(qf[mi][1], k1, s, 0,0,0);
                S[mi][nt] = s;
            }
        }
        // V fragments direct from global (B-frag layout: row=d, k=key)
        short8 vf[2][4];
        #pragma unroll
        for (int ks=0; ks<2; ++ks)
            #pragma unroll
            for (int nt=0;nt<4;nt++)
                vf[ks][nt] = *(const short8*)(Vg + (size_t)(nt*16 + l16)*L_ + kt*64 + ks*32 + quad*8);

        if (gated) {
            #pragma unroll
            for (int nt=0; nt<4; ++nt){
                short8 g0 = frag64(sGKc, nt*16 + l16, quad);
                short8 g1 = frag64(sGKc, nt*16 + l16, 4 + quad);
                #pragma unroll
                for (int mi=0; mi<2; ++mi){
                    float4v g = {};
                    g = __builtin_amdgcn_mfma_f32_16x16x32_bf16(gqf[mi][0], g0, g, 0,0,0);
                    g = __builtin_amdgcn_mfma_f32_16x16x32_bf16(gqf[mi][1], g1, g, 0,0,0);
                    #pragma unroll
                    for (int r=0;r<4;r++){
                        float sig = 1.f/(1.f + __expf(-g[r]));
                        S[mi][nt][r] = 0.125f*S[mi][nt][r] - 1.25f*sig;
                    }
                }
            }
        } else {
            #pragma unroll
            for (int mi=0;mi<2;mi++)
                #pragma unroll
                for (int nt=0;nt<4;nt++)
                    #pragma unroll
                    for (int r=0;r<4;r++) S[mi][nt][r] = 0.125f*S[mi][nt][r] - 0.625f;
        }
        // + mask, exp (fixed m=0), in-lane l accumulation; per-mi P->LDS + PV
        #pragma unroll
        for (int mi=0;mi<2;mi++){
            #pragma unroll
            for (int nt=0;nt<4;nt++){
                float mv = sMask[kt*64 + nt*16 + l16];
                #pragma unroll
                for (int r=0;r<4;r++){
                    float p = __expf(S[mi][nt][r] + mv);
                    S[mi][nt][r] = p;
                    lrow[mi][r] += p;
                }
            }
            // P tile (bf16) -> swizzled LDS, wave-local 16 rows
            #pragma unroll
            for (int nt=0;nt<4;nt++)
                #pragma unroll
                for (int r=0;r<4;r++){
                    int row = wave*16 + quad*4 + r;
                    int col = nt*16 + l16;
                    int j = col >> 3, jo = col & 7;
                    sP[(row<<6) + (((j ^ (row & 7))<<3) | jo)] = f2bf(S[mi][nt][r]);
                }
            // O += P V  (wave-local sP read; in-order DS pipe, no barrier)
            #pragma unroll
            for (int ks=0; ks<2; ++ks){
                short8 pf = frag64(sP, wave*16 + l16, ks*4 + quad);
                #pragma unroll
                for (int nt=0;nt<4;nt++)
                    O[mi][nt] = __builtin_amdgcn_mfma_f32_16x16x32_bf16(pf, vf[ks][nt], O[mi][nt], 0,0,0);
            }
        }
        __syncthreads();   // sKc free for next prefetch; sKn drained
    };

    for (int k2 = 0; k2 < 10; k2 += 2){
        step(k2,   sK0, sGK0, sK1, sGK1);
        step(k2+1, sK1, sGK1, sK0, sGK0);
    }

    // final l reduction across the 16 lanes holding each row's columns
    #pragma unroll
    for (int mi=0;mi<2;mi++)
        #pragma unroll
        for (int r=0;r<4;r++){
            float s = lrow[mi][r];
            #pragma unroll
            for (int off=1; off<16; off<<=1) s += __shfl_xor(s, off, 64);
            lrow[mi][r] = 1.f/s;
        }

    #pragma unroll
    for (int mi=0;mi<2;mi++){
        int q0 = qt*128 + wave*32 + mi*16 + quad*4;
        #pragma unroll
        for (int nt=0;nt<4;nt++){
            int d = h*DH_ + nt*16 + l16;
            #pragma unroll
            for (int r=0;r<4;r++){
                int q = q0 + r;
                float v = O[mi][nt][r]*lrow[mi][r];
                size_t off;
                if (q < LW_) off = ((size_t)(b*LW_ + q))*D_ + d;
                else         off = (size_t)B_*LW_*D_ + ((size_t)(b*LE_ + (q-LW_)))*D_ + d;
                out[off] = v;
            }
        }
    }
}

extern "C" void kernel_launch(void* const* d_in, const int* in_sizes, int n_in,
                              void* d_out, int out_size, void* d_ws, size_t ws_size,
                              hipStream_t stream)
{
    const float* word  = (const float*)d_in[0];
    const float* ent   = (const float*)d_in[1];
    const float* mask  = (const float*)d_in[2];
    const float* qw    = (const float*)d_in[4];  const float* qb_   = (const float*)d_in[5];
    const float* kw    = (const float*)d_in[6];  const float* kb_   = (const float*)d_in[7];
    const float* vw    = (const float*)d_in[8];  const float* vb_   = (const float*)d_in[9];
    const float* w2eqw = (const float*)d_in[10]; const float* w2eqb = (const float*)d_in[11];
    const float* w2ekw = (const float*)d_in[12]; const float* w2ekb = (const float*)d_in[13];
    const float* e2wqw = (const float*)d_in[14]; const float* e2wqb = (const float*)d_in[15];
    const float* e2wkw = (const float*)d_in[16]; const float* e2wkb = (const float*)d_in[17];

    char* ws = (char*)d_ws;
    unsigned short* hb      = (unsigned short*)(ws);                 // 20,971,520 B
    unsigned short* bt      = (unsigned short*)(ws + 20971520);      // 14,680,064 B
    float*          biasAll = (float*)        (ws + 35651584);       //     28,672 B
    unsigned short* C       = (unsigned short*)(ws + 35680256);      // 146,800,640 B
    unsigned short* Vt      = (unsigned short*)(ws + 182480896);     // 20,971,520 B  (end ~203.5 MB)

    prep_h   <<<5148, 256, 0, stream>>>(word, ent, hb,
                                        qb_, kb_, vb_, w2eqb, w2ekb, e2wqb, e2wkb, biasAll);
    prep_w   <<<1792, 256, 0, stream>>>(qw, kw, vw, w2eqw, w2ekw, e2wqw, e2wkw, bt);
    gemm_proj<<<3200, 256, 0, stream>>>(hb, bt, biasAll, C, Vt);
    attn     <<<1280, 256, 0, stream>>>(C, Vt, mask, (float*)d_out);
}

// Round 6
// 413.160 us; speedup vs baseline: 1.1795x; 1.1795x over previous
//
#include <hip/hip_runtime.h>
#include <hip/hip_bf16.h>
#include <stdint.h>

#define B_   16
#define LW_  512
#define LE_  128
#define L_   640
#define D_   1024
#define H_   16
#define DH_  64
#define M_   (B_*L_)     // 10240
#define N_   (7*D_)      // 7168
#define K_   D_          // 1024

typedef __attribute__((ext_vector_type(8))) short short8;
typedef __attribute__((ext_vector_type(4))) float float4v;

__device__ __forceinline__ unsigned short f2bf(float x){
    union { float f; uint32_t u; } v; v.f = x;
    uint32_t u = v.u;
    return (unsigned short)((u + 0x7FFFu + ((u >> 16) & 1u)) >> 16);
}

// ------- prep: concat + cast hidden states to bf16 (+ fused bias concat) ----
__global__ __launch_bounds__(256) void prep_h(const float* __restrict__ word,
                                              const float* __restrict__ ent,
                                              unsigned short* __restrict__ hb,
                                              const float* __restrict__ b0, const float* __restrict__ b1,
                                              const float* __restrict__ b2, const float* __restrict__ b3,
                                              const float* __restrict__ b4, const float* __restrict__ b5,
                                              const float* __restrict__ b6,
                                              float* __restrict__ biasAll){
    if (blockIdx.x >= 5120) {
        int n = (blockIdx.x - 5120)*256 + threadIdx.x;   // 0..7167
        int p = n >> 10, c = n & 1023;
        const float* bp = (p==0)?b0:(p==1)?b1:(p==2)?b2:(p==3)?b3:(p==4)?b4:(p==5)?b5:b6;
        biasAll[n] = bp[c];
        return;
    }
    int idx = blockIdx.x*256 + threadIdx.x;   // one 8-elem group
    int row = idx >> 7;                       // 128 groups per 1024-row
    int c   = (idx & 127) << 3;
    int b = row / L_, l = row - b*L_;
    const float* src = (l < LW_) ? (word + ((size_t)b*LW_ + l)*D_ + c)
                                 : (ent  + ((size_t)b*LE_ + (l-LW_))*D_ + c);
    float4 a0 = ((const float4*)src)[0];
    float4 a1 = ((const float4*)src)[1];
    uint4 o;
    o.x = f2bf(a0.x) | ((uint32_t)f2bf(a0.y)<<16);
    o.y = f2bf(a0.z) | ((uint32_t)f2bf(a0.w)<<16);
    o.z = f2bf(a1.x) | ((uint32_t)f2bf(a1.y)<<16);
    o.w = f2bf(a1.z) | ((uint32_t)f2bf(a1.w)<<16);
    *(uint4*)(hb + (size_t)row*D_ + c) = o;
}

// ---------------- prep: transpose + cast weights -> Bt[7168][1024] bf16 ----
__global__ __launch_bounds__(256) void prep_w(const float* __restrict__ w0, const float* __restrict__ w1,
                                              const float* __restrict__ w2, const float* __restrict__ w3,
                                              const float* __restrict__ w4, const float* __restrict__ w5,
                                              const float* __restrict__ w6,
                                              unsigned short* __restrict__ bt){
    __shared__ float t[64][65];
    int id = blockIdx.x;
    int kt = id & 15;           // 16 k-tiles of 64
    int ntile = id >> 4;        // 112 n-tiles of 64
    int p = ntile >> 4;         // projection index
    int nin = (ntile & 15) * 64;
    const float* wp = (p==0)?w0:(p==1)?w1:(p==2)?w2:(p==3)?w3:(p==4)?w4:(p==5)?w5:w6;
    int k0 = kt*64;
    int tr  = threadIdx.x >> 4;        // 0..15
    int tc4 = (threadIdx.x & 15) * 4;  // 0..60
    for (int pass = 0; pass < 4; ++pass){
        int kl = pass*16 + tr;
        const float4 v = *(const float4*)(wp + (size_t)(k0+kl)*D_ + nin + tc4);
        t[kl][tc4+0]=v.x; t[kl][tc4+1]=v.y; t[kl][tc4+2]=v.z; t[kl][tc4+3]=v.w;
    }
    __syncthreads();
    for (int pass = 0; pass < 4; ++pass){
        int nl = pass*16 + tr;
        uint2 pk;
        pk.x = f2bf(t[tc4+0][nl]) | ((uint32_t)f2bf(t[tc4+1][nl])<<16);
        pk.y = f2bf(t[tc4+2][nl]) | ((uint32_t)f2bf(t[tc4+3][nl])<<16);
        *(uint2*)(bt + (size_t)(ntile*64 + nl)*K_ + k0 + tc4) = pk;
    }
}

// ---------------- projection GEMM (packed tile list, head-split outputs) ----
// Outputs (bf16):
//   Qt / Kt / GQt / GKt : [b,h,l,64] contiguous per (b,h)   (row stride 128 B)
//   GQt rows: l<512 <- proj3 (w2e_q), l>=512 <- proj5 (e2w_q)
//   GKt rows: l<512 <- proj6 (e2w_k), l>=512 <- proj4 (w2e_k)
//   Vt2 : [b,h,kt,d,64] 64x64 tiles contiguous
__global__ __launch_bounds__(256, 4) void gemm_proj(const unsigned short* __restrict__ hb,
                                                    const unsigned short* __restrict__ bt,
                                                    const float* __restrict__ biasAll,
                                                    unsigned short* __restrict__ Qt,
                                                    unsigned short* __restrict__ Kt,
                                                    unsigned short* __restrict__ GQt,
                                                    unsigned short* __restrict__ GKt,
                                                    unsigned short* __restrict__ Vt2){
    __shared__ unsigned short sA[128*64];
    __shared__ unsigned short sB[128*64];
    int tid = threadIdx.x;
    int wave = tid >> 6, lane = tid & 63;
    int quad = lane >> 4, l16 = lane & 15;

    int bid = blockIdx.x;
    int m0, n0;
    if (bid < 1920) { int bm = bid % 80, bn = bid / 80; m0 = bm*128; n0 = bn*128; }
    else {
        int g = bid - 1920;
        if (g < 512)      { int mt = g & 63; m0 = (mt>>2)*640 + (mt&3)*128; n0 = 3072 + (g>>6)*128; }
        else if (g < 640) { int e = g-512;   m0 = (e&15)*640 + 512;         n0 = 4096 + (e>>4)*128; }
        else if (g < 768) { int e = g-640;   m0 = (e&15)*640 + 512;         n0 = 5120 + (e>>4)*128; }
        else              { int e = g-768; int mt = e & 63;
                            m0 = (mt>>2)*640 + (mt&3)*128;                  n0 = 6144 + (e>>6)*128; }
    }

    int wm = wave >> 1, wn = wave & 1;
    float4v acc[4][4] = {};

    for (int kk = 0; kk < K_; kk += 64) {
        #pragma unroll
        for (int i = 0; i < 4; ++i) {
            int idx = i*256 + tid;
            int row = idx >> 3;
            int c8  = (((idx & 7) ^ (row & 7)) << 3);   // swizzled global chunk
            const unsigned short* ga = hb + (size_t)(m0 + row)*K_ + kk + c8;
            __builtin_amdgcn_global_load_lds(
                (const __attribute__((address_space(1))) void*)ga,
                (__attribute__((address_space(3))) void*)(sA + ((i*256 + wave*64) << 3)), 16, 0, 0);
            const unsigned short* gb = bt + (size_t)(n0 + row)*K_ + kk + c8;
            __builtin_amdgcn_global_load_lds(
                (const __attribute__((address_space(1))) void*)gb,
                (__attribute__((address_space(3))) void*)(sB + ((i*256 + wave*64) << 3)), 16, 0, 0);
        }
        __syncthreads();
        #pragma unroll
        for (int s = 0; s < 2; ++s) {
            short8 af[4], bf[4];
            #pragma unroll
            for (int i=0;i<4;i++){
                int row = wm*64 + i*16 + l16;
                af[i] = *(const short8*)(sA + (row << 6) + (((s*4 + quad) ^ (row & 7)) << 3));
            }
            #pragma unroll
            for (int j=0;j<4;j++){
                int row = wn*64 + j*16 + l16;
                bf[j] = *(const short8*)(sB + (row << 6) + (((s*4 + quad) ^ (row & 7)) << 3));
            }
            #pragma unroll
            for (int i=0;i<4;i++)
                #pragma unroll
                for (int j=0;j<4;j++)
                    acc[i][j] = __builtin_amdgcn_mfma_f32_16x16x32_bf16(af[i], bf[j], acc[i][j], 0,0,0);
        }
        __syncthreads();
    }

    int pidx = n0 >> 10;   // projection index (uniform per block)
    #pragma unroll
    for (int i=0;i<4;i++){
        int mrow = m0 + wm*64 + i*16 + quad*4;
        int bb = mrow / L_, l = mrow - bb*L_;       // 4 rows stay in one b (mrow%4==0)
        #pragma unroll
        for (int j=0;j<4;j++){
            int ncol = n0 + wn*64 + j*16 + l16;
            int hc = ncol & 1023;
            int hh = hc >> 6, dh = hc & 63;
            float bias = biasAll[ncol];
            size_t bh = (size_t)(bb*H_ + hh);
            if (pidx == 2) {                         // V -> tile-blocked transpose
                int kt = l >> 6, key = l & 63;
                uint2 pk;
                pk.x = f2bf(acc[i][j][0]+bias) | ((uint32_t)f2bf(acc[i][j][1]+bias)<<16);
                pk.y = f2bf(acc[i][j][2]+bias) | ((uint32_t)f2bf(acc[i][j][3]+bias)<<16);
                *(uint2*)(Vt2 + ((bh*10 + kt)<<12) + (dh<<6) + key) = pk;
            } else {
                unsigned short* base = (pidx==0) ? Qt : (pidx==1) ? Kt
                                     : (pidx==3 || pidx==5) ? GQt : GKt;
                #pragma unroll
                for (int r=0;r<4;r++)
                    base[(bh*L_ + l + r)*DH_ + dh] = f2bf(acc[i][j][r] + bias);
            }
        }
    }
}

// ---------------- fused gated flash attention (v6) -------------------------
// No staging LDS, no __syncthreads. All fragments load direct from global in
// coalesced 2KB/instruction reads (head-split layouts). Only LDS: 8KB
// wave-local sP round-trip (C-layout -> A-layout). XCD-swizzled block ids.

__device__ __forceinline__ short8 fragP(const unsigned short* lds, int row, int jj){
    return *(const short8*)(lds + (row << 6) + (((jj ^ (row & 7)) << 3)));
}

__global__ __launch_bounds__(256) void attn(const unsigned short* __restrict__ Qt,
                                            const unsigned short* __restrict__ Kt,
                                            const unsigned short* __restrict__ GQt,
                                            const unsigned short* __restrict__ GKt,
                                            const unsigned short* __restrict__ Vt2,
                                            const float* __restrict__ mask,
                                            float* __restrict__ out){
    int x = blockIdx.x;
    int t = x >> 3;
    int qt = t % 5;
    int p  = (t/5)*8 + (x & 7);       // same (b,h): all 5 qt share id%8 -> same XCD
    int b = p >> 4, h = p & 15;
    bool isWord = (qt < 4);
    int tid = threadIdx.x, wave = tid>>6, lane = tid&63, quad = lane>>4, l16 = lane&15;

    __shared__ unsigned short sP[64*64];   // wave-local rows only

    const unsigned short* Qb  = Qt  + (size_t)p*L_*DH_;
    const unsigned short* Kb  = Kt  + (size_t)p*L_*DH_;
    const unsigned short* GQb = GQt + (size_t)p*L_*DH_;
    const unsigned short* GKb = GKt + (size_t)p*L_*DH_;
    const unsigned short* Vb  = Vt2 + ((size_t)p*10 << 12);
    const float* mb = mask + b*L_;

    // Q / gateQ A-fragments (persist across k-loop)
    int q0 = qt*128 + wave*32;
    short8 qf[2][2], gqf[2][2];
    #pragma unroll
    for (int mi=0; mi<2; ++mi){
        const unsigned short* qp = Qb  + (size_t)(q0 + mi*16 + l16)*DH_;
        const unsigned short* gp = GQb + (size_t)(q0 + mi*16 + l16)*DH_;
        qf[mi][0]  = *(const short8*)(qp + quad*8);
        qf[mi][1]  = *(const short8*)(qp + 32 + quad*8);
        gqf[mi][0] = *(const short8*)(gp + quad*8);
        gqf[mi][1] = *(const short8*)(gp + 32 + quad*8);
    }

    float4v O[2][4] = {};
    float lrow[2][4] = {};

    for (int kt = 0; kt < 10; ++kt) {
        bool gated = isWord ? (kt >= 8) : (kt < 8);

        // K fragments (coalesced 2KB/instr)
        short8 kf[2][4];
        #pragma unroll
        for (int nt=0;nt<4;nt++){
            const unsigned short* kp = Kb + (size_t)(kt*64 + nt*16 + l16)*DH_;
            kf[0][nt] = *(const short8*)(kp + quad*8);
            kf[1][nt] = *(const short8*)(kp + 32 + quad*8);
        }
        // V fragments (tile-blocked, coalesced)
        short8 vf[2][4];
        #pragma unroll
        for (int nt=0;nt<4;nt++){
            const unsigned short* vp = Vb + (kt<<12) + ((nt*16 + l16)<<6);
            vf[0][nt] = *(const short8*)(vp + quad*8);
            vf[1][nt] = *(const short8*)(vp + 32 + quad*8);
        }
        // mask values
        float mv[4];
        #pragma unroll
        for (int nt=0;nt<4;nt++) mv[nt] = mb[kt*64 + nt*16 + l16];

        // S = Q K^T
        float4v S[2][4];
        #pragma unroll
        for (int nt=0; nt<4; ++nt)
            #pragma unroll
            for (int mi=0; mi<2; ++mi){
                float4v s = {};
                s = __builtin_amdgcn_mfma_f32_16x16x32_bf16(qf[mi][0], kf[0][nt], s, 0,0,0);
                s = __builtin_amdgcn_mfma_f32_16x16x32_bf16(qf[mi][1], kf[1][nt], s, 0,0,0);
                S[mi][nt] = s;
            }
        if (gated) {
            #pragma unroll
            for (int nt=0; nt<4; ++nt){
                const unsigned short* gp = GKb + (size_t)(kt*64 + nt*16 + l16)*DH_;
                short8 g0 = *(const short8*)(gp + quad*8);
                short8 g1 = *(const short8*)(gp + 32 + quad*8);
                #pragma unroll
                for (int mi=0; mi<2; ++mi){
                    float4v g = {};
                    g = __builtin_amdgcn_mfma_f32_16x16x32_bf16(gqf[mi][0], g0, g, 0,0,0);
                    g = __builtin_amdgcn_mfma_f32_16x16x32_bf16(gqf[mi][1], g1, g, 0,0,0);
                    #pragma unroll
                    for (int r=0;r<4;r++){
                        float sig = 1.f/(1.f + __expf(-g[r]));
                        S[mi][nt][r] = 0.125f*S[mi][nt][r] - 1.25f*sig;
                    }
                }
            }
        } else {
            #pragma unroll
            for (int mi=0;mi<2;mi++)
                #pragma unroll
                for (int nt=0;nt<4;nt++)
                    #pragma unroll
                    for (int r=0;r<4;r++) S[mi][nt][r] = 0.125f*S[mi][nt][r] - 0.625f;
        }
        // exp (fixed m=0), in-lane l accumulation; per-mi P->LDS + PV
        #pragma unroll
        for (int mi=0;mi<2;mi++){
            #pragma unroll
            for (int nt=0;nt<4;nt++)
                #pragma unroll
                for (int r=0;r<4;r++){
                    float pv = __expf(S[mi][nt][r] + mv[nt]);
                    S[mi][nt][r] = pv;
                    lrow[mi][r] += pv;
                }
            // P tile (bf16) -> swizzled LDS, wave-local 16 rows
            #pragma unroll
            for (int nt=0;nt<4;nt++)
                #pragma unroll
                for (int r=0;r<4;r++){
                    int row = wave*16 + quad*4 + r;
                    int col = nt*16 + l16;
                    int j = col >> 3, jo = col & 7;
                    sP[(row<<6) + (((j ^ (row & 7))<<3) | jo)] = f2bf(S[mi][nt][r]);
                }
            // O += P V  (wave-local sP; in-order DS pipe, no barrier)
            #pragma unroll
            for (int ks=0; ks<2; ++ks){
                short8 pf = fragP(sP, wave*16 + l16, ks*4 + quad);
                #pragma unroll
                for (int nt=0;nt<4;nt++)
                    O[mi][nt] = __builtin_amdgcn_mfma_f32_16x16x32_bf16(pf, vf[ks][nt], O[mi][nt], 0,0,0);
            }
        }
    }

    // final l reduction across the 16 lanes holding each row's columns
    #pragma unroll
    for (int mi=0;mi<2;mi++)
        #pragma unroll
        for (int r=0;r<4;r++){
            float s = lrow[mi][r];
            #pragma unroll
            for (int off=1; off<16; off<<=1) s += __shfl_xor(s, off, 64);
            lrow[mi][r] = 1.f/s;
        }

    #pragma unroll
    for (int mi=0;mi<2;mi++){
        int qr = qt*128 + wave*32 + mi*16 + quad*4;
        #pragma unroll
        for (int nt=0;nt<4;nt++){
            int d = h*DH_ + nt*16 + l16;
            #pragma unroll
            for (int r=0;r<4;r++){
                int q = qr + r;
                float v = O[mi][nt][r]*lrow[mi][r];
                size_t off;
                if (q < LW_) off = ((size_t)(b*LW_ + q))*D_ + d;
                else         off = (size_t)B_*LW_*D_ + ((size_t)(b*LE_ + (q-LW_)))*D_ + d;
                out[off] = v;
            }
        }
    }
}

extern "C" void kernel_launch(void* const* d_in, const int* in_sizes, int n_in,
                              void* d_out, int out_size, void* d_ws, size_t ws_size,
                              hipStream_t stream)
{
    const float* word  = (const float*)d_in[0];
    const float* ent   = (const float*)d_in[1];
    const float* mask  = (const float*)d_in[2];
    const float* qw    = (const float*)d_in[4];  const float* qb_   = (const float*)d_in[5];
    const float* kw    = (const float*)d_in[6];  const float* kb_   = (const float*)d_in[7];
    const float* vw    = (const float*)d_in[8];  const float* vb_   = (const float*)d_in[9];
    const float* w2eqw = (const float*)d_in[10]; const float* w2eqb = (const float*)d_in[11];
    const float* w2ekw = (const float*)d_in[12]; const float* w2ekb = (const float*)d_in[13];
    const float* e2wqw = (const float*)d_in[14]; const float* e2wqb = (const float*)d_in[15];
    const float* e2wkw = (const float*)d_in[16]; const float* e2wkb = (const float*)d_in[17];

    char* ws = (char*)d_ws;
    unsigned short* hb      = (unsigned short*)(ws);                 // 20,971,520 B
    unsigned short* bt      = (unsigned short*)(ws + 20971520);      // 14,680,064 B
    float*          biasAll = (float*)        (ws + 35651584);       //     28,672 B
    unsigned short* Qt      = (unsigned short*)(ws + 35680256);      // 20,971,520 B
    unsigned short* Kt      = (unsigned short*)(ws + 56651776);      // 20,971,520 B
    unsigned short* GQt     = (unsigned short*)(ws + 77623296);      // 20,971,520 B
    unsigned short* GKt     = (unsigned short*)(ws + 98594816);      // 20,971,520 B
    unsigned short* Vt2     = (unsigned short*)(ws + 119566336);     // 20,971,520 B (end ~140.5 MB)

    prep_h   <<<5148, 256, 0, stream>>>(word, ent, hb,
                                        qb_, kb_, vb_, w2eqb, w2ekb, e2wqb, e2wkb, biasAll);
    prep_w   <<<1792, 256, 0, stream>>>(qw, kw, vw, w2eqw, w2ekw, e2wqw, e2wkw, bt);
    gemm_proj<<<3200, 256, 0, stream>>>(hb, bt, biasAll, Qt, Kt, GQt, GKt, Vt2);
    attn     <<<1280, 256, 0, stream>>>(Qt, Kt, GQt, GKt, Vt2, mask, (float*)d_out);
}